// Round 10
// baseline (202.518 us; speedup 1.0000x reference)
//
#include <hip/hip_runtime.h>

#define Bn 2
#define Ln 4096
#define Hn 8
#define Dn 64
#define NMEGA 32           // 128-key mega-tiles
#define BH_STRIDE 262144   // halves per bh in kp/vp

typedef float    f32x4  __attribute__((ext_vector_type(4)));
typedef float    f32x16 __attribute__((ext_vector_type(16)));
typedef _Float16 f16x2  __attribute__((ext_vector_type(2)));
typedef _Float16 f16x8  __attribute__((ext_vector_type(8)));
typedef unsigned int u32;
typedef u32 u32x2 __attribute__((ext_vector_type(2)));
typedef u32 u32x4 __attribute__((ext_vector_type(4)));

static __device__ __forceinline__ u32 pkf16(float a, float b){
    auto h = __builtin_amdgcn_cvt_pkrtz(a, b);   // v_cvt_pkrtz_f16_f32
    return __builtin_bit_cast(u32, h);
}

static __device__ __forceinline__ u32x2 swp(u32 a, u32 b){
    auto r = __builtin_amdgcn_permlane32_swap(a, b, false, false);
    return __builtin_bit_cast(u32x2, r);
}

// ---- fused prep: pack K and V^T into 32x32x16-MFMA fragment-major layout ----
// (unchanged — verified passing R4/R5/R6/R8)
__global__ __launch_bounds__(256)
void kvprep(const float* __restrict__ Kg, const float* __restrict__ Vg,
            _Float16* __restrict__ kp, _Float16* __restrict__ vp){
    __shared__ float tV[64*65];
    const int t = blockIdx.x, bh = blockIdx.y, b = bh>>3, h = bh&7;
    const int tid = threadIdx.x;
#pragma unroll
    for(int i=0;i<4;++i){
        int idx = tid + i*256;
        int k = idx >> 4, d4 = (idx & 15)*4;
        float4 v = *(const float4*)(Vg + (((size_t)b*Ln + t*64 + k)*Hn + h)*Dn + d4);
        tV[k*65+d4+0]=v.x; tV[k*65+d4+1]=v.y;
        tV[k*65+d4+2]=v.z; tV[k*65+d4+3]=v.w;
    }
#pragma unroll
    for(int i=0;i<2;++i){
        int u = tid + i*256;
        int lane = u & 63, unit = u >> 6;
        int g = unit >> 2, cc = unit & 3;
        const float* src = Kg + (((size_t)b*Ln + t*64 + g*32 + (lane&31))*Hn + h)*Dn
                         + cc*16 + (lane>>5)*8;
        float4 a = *(const float4*)src;
        float4 c4 = *(const float4*)(src + 4);
        f16x8 o;
        o[0]=(_Float16)a.x;  o[1]=(_Float16)a.y;  o[2]=(_Float16)a.z;  o[3]=(_Float16)a.w;
        o[4]=(_Float16)c4.x; o[5]=(_Float16)c4.y; o[6]=(_Float16)c4.z; o[7]=(_Float16)c4.w;
        *(f16x8*)(kp + (size_t)bh*BH_STRIDE + (size_t)t*4096 + (size_t)u*8) = o;
    }
    __syncthreads();
#pragma unroll
    for(int i=0;i<2;++i){
        int u = tid + i*256;
        int lane = u & 63, unit = u >> 6;
        int g = unit >> 2, kh = (unit >> 1) & 1, dt = unit & 1;
        int krow = g*32 + kh*16 + (lane>>5)*8;
        int d = dt*32 + (lane&31);
        f16x8 o;
#pragma unroll
        for(int j=0;j<8;++j) o[j] = (_Float16)tV[(krow+j)*65 + d];
        *(f16x8*)(vp + (size_t)bh*BH_STRIDE + (size_t)t*4096 + (size_t)u*8) = o;
    }
}

// QK: 4-deep 32x32x16 chain from zero accumulator
static __device__ __forceinline__ f32x16 qk4(const f16x8 (&kf)[4], const f16x8 (&qf)[4]){
    f32x16 s;
#pragma unroll
    for(int r=0;r<16;++r) s[r]=0.f;
    s = __builtin_amdgcn_mfma_f32_32x32x16_f16(kf[0], qf[0], s, 0,0,0);
    s = __builtin_amdgcn_mfma_f32_32x32x16_f16(kf[1], qf[1], s, 0,0,0);
    s = __builtin_amdgcn_mfma_f32_32x32x16_f16(kf[2], qf[2], s, 0,0,0);
    s = __builtin_amdgcn_mfma_f32_32x32x16_f16(kf[3], qf[3], s, 0,0,0);
    return s;
}

// finish: exp2 -> pack (cvt_pkrtz + permlane32_swap) -> consistent-l via fdot2
// -> PV accumulate. Identical op set/order to R4/R5/R8 (passing numerics).
static __device__ __forceinline__ void finish_pv(const f32x16& S, float& lac,
                                                 f32x16& o0, f32x16& o1,
                                                 const f16x8 (&vf)[4]){
    f32x16 p;
#pragma unroll
    for(int r=0;r<16;++r) p[r] = __builtin_amdgcn_exp2f(S[r]);
    u32 A0 = pkf16(p[0],p[1]),   A1 = pkf16(p[2],p[3]);
    u32 B0 = pkf16(p[4],p[5]),   B1 = pkf16(p[6],p[7]);
    u32 C0 = pkf16(p[8],p[9]),   C1 = pkf16(p[10],p[11]);
    u32 D0 = pkf16(p[12],p[13]), D1 = pkf16(p[14],p[15]);
    u32x2 r0 = swp(A0,B0), r1 = swp(A1,B1);
    u32x2 r2 = swp(C0,D0), r3 = swp(C1,D1);
    u32x4 w0 = {r0.x, r1.x, r0.y, r1.y};   // keys [0,16) of this 32-key group
    u32x4 w1 = {r2.x, r3.x, r2.y, r3.y};   // keys [16,32)
    f16x8 pa0 = __builtin_bit_cast(f16x8, w0);
    f16x8 pa1 = __builtin_bit_cast(f16x8, w1);
    const f16x2 ones = {(_Float16)1.0f, (_Float16)1.0f};
#pragma unroll
    for(int j=0;j<4;++j){
        f16x2 c0 = {pa0[2*j], pa0[2*j+1]};
        f16x2 c1 = {pa1[2*j], pa1[2*j+1]};
        lac = __builtin_amdgcn_fdot2(c0, ones, lac, false);
        lac = __builtin_amdgcn_fdot2(c1, ones, lac, false);
    }
    // vf[j], j = kh*2+dt
    o0 = __builtin_amdgcn_mfma_f32_32x32x16_f16(pa0, vf[0], o0, 0,0,0);
    o0 = __builtin_amdgcn_mfma_f32_32x32x16_f16(pa1, vf[2], o0, 0,0,0);
    o1 = __builtin_amdgcn_mfma_f32_32x32x16_f16(pa0, vf[1], o1, 0,0,0);
    o1 = __builtin_amdgcn_mfma_f32_32x32x16_f16(pa1, vf[3], o1, 0,0,0);
}

// load 4 fragment registers (b128 each) from fragment-major global
static __device__ __forceinline__ void ld4(f16x8 (&dst)[4], const char* base, int off){
#pragma unroll
    for(int i=0;i<4;++i) dst[i] = *(const f16x8*)(base + ((off+i)<<10));
}

// ---- main kernel: no-LDS free-run (R8) at R4's work split -> 4 waves/SIMD ----
// 8 waves/block: kh2=wv&1 (64-key half), qh=wv>>1 in [0,4) (32-query tile).
// 4096 waves total = 4 waves/SIMD of INDEPENDENT free-running waves (R2/R4
// had 4/SIMD but barrier-convoyed; R8 was free-running but only 2/SIMD).
// Fragments read directly from fragment-major kp/vp (L2-resident: XCD bh%8
// holds this bh's 1 MB). No main-loop barriers. LDS = 33 KB epilogue only.
// __launch_bounds__ empirical cap map (R2/R5/R6/R7/R9): arg -> 256/arg cap;
// arg=1 additionally HALVED residency (R9) -> use (512,2): cap 128 >= ~110
// needed for this halved per-wave state. Per-wave compute order == R4.
__global__ __launch_bounds__(512,2)
void attn_fwd(const float* __restrict__ Qg, float* __restrict__ Og,
              const _Float16* __restrict__ kp, const _Float16* __restrict__ vp){
    __shared__ __align__(16) float xo[4*32*64 + 128];   // epilogue combine

    const int tid  = threadIdx.x;
    const int lane = tid & 63, wv = tid >> 6;
    const int kh2 = wv & 1, qh = wv >> 1;          // qh in [0,4)
    const int l31 = lane & 31, hi = lane >> 5;
    const int bh = blockIdx.x, b = bh>>3, h = bh&7;
    const int q0 = blockIdx.y*128 + qh*32;

    const float c = 0.125f * 1.4426950408889634f;    // scale * log2(e)

    // Q B-frags: lane holds query=l31, d = cc*16 + hi*8 + j
    f16x8 qf[4];
    {
        const float* qrow = Qg + (((size_t)b*Ln + q0 + l31)*Hn + h)*Dn;
#pragma unroll
        for(int cc=0;cc<4;++cc){
            const float* p4 = qrow + cc*16 + hi*8;
            float4 x = *(const float4*)p4;
            float4 y = *(const float4*)(p4+4);
            f16x8 f;
            f[0]=(_Float16)(x.x*c); f[1]=(_Float16)(x.y*c);
            f[2]=(_Float16)(x.z*c); f[3]=(_Float16)(x.w*c);
            f[4]=(_Float16)(y.x*c); f[5]=(_Float16)(y.y*c);
            f[6]=(_Float16)(y.z*c); f[7]=(_Float16)(y.w*c);
            qf[cc]=f;
        }
    }

    f32x16 o0, o1;
    float lac = 0.f;
#pragma unroll
    for(int r=0;r<16;++r){ o0[r]=0.f; o1[r]=0.f; }

    // per-lane global base of this wave's 64-key half within each mega-tile:
    // mega-tile stride 16 KB; within it: kh2 half (8 KB), unit (1 KB), lane*16.
    const char* kgc = (const char*)(kp + (size_t)bh*BH_STRIDE) + kh2*8192 + lane*16;
    const char* vgc = (const char*)(vp + (size_t)bh*BH_STRIDE) + kh2*8192 + lane*16;

    for(int T=0; T<NMEGA; ++T){
        const char* Kb = kgc + (size_t)T*16384;
        const char* Vb = vgc + (size_t)T*16384;

        f16x8 kf0[4], vf0[4];
        ld4(kf0, Kb, 0); ld4(vf0, Vb, 0);
        f32x16 S0 = qk4(kf0, qf);             // g=0

        f16x8 kf1[4], vf1[4];
        ld4(kf1, Kb, 4); ld4(vf1, Vb, 4);
        finish_pv(S0, lac, o0, o1, vf0);

        f32x16 S1 = qk4(kf1, qf);             // g=1
        finish_pv(S1, lac, o0, o1, vf1);
    }

    // ---- reduce l within wave: lanes l and l+32 cover complementary key slots ----
    float lred = lac + __shfl_xor(lac, 32, 64);

    // ---- epilogue: combine kh2 halves through LDS (R4's verified layout) ----
    float* xl = xo + 4*32*64;
    if(kh2){
#pragma unroll
        for(int r=0;r<16;++r){
            int qr = (r&3) + 8*(r>>2) + 4*hi;
            xo[(qh*32 + qr)*64 +  0 + l31] = o0[r];
            xo[(qh*32 + qr)*64 + 32 + l31] = o1[r];
        }
        if(hi==0) xl[qh*32 + l31] = lred;
    }
    __syncthreads();
    if(!kh2){
        float inv = 1.0f/(lred + xl[qh*32 + l31]);
        float* ob = Og + (((size_t)b*Ln + q0)*Hn + h)*Dn;
#pragma unroll
        for(int r=0;r<16;++r){
            int qr = (r&3) + 8*(r>>2) + 4*hi;
            float invr = __shfl(inv, qr, 64);   // lane qr holds query qr's inv
            float v0 = o0[r] + xo[(qh*32 + qr)*64 +  0 + l31];
            float v1 = o1[r] + xo[(qh*32 + qr)*64 + 32 + l31];
            ob[(size_t)qr*Hn*Dn +  0 + l31] = v0*invr;
            ob[(size_t)qr*Hn*Dn + 32 + l31] = v1*invr;
        }
    }
}

extern "C" void kernel_launch(void* const* d_in, const int* in_sizes, int n_in,
                              void* d_out, int out_size, void* d_ws, size_t ws_size,
                              hipStream_t stream) {
    const float* Q = (const float*)d_in[0];
    const float* K = (const float*)d_in[1];
    const float* V = (const float*)d_in[2];
    float* O = (float*)d_out;

    _Float16* kp = (_Float16*)d_ws;                        // 8 MB
    _Float16* vp = (_Float16*)((char*)d_ws + (8u<<20));    // 8 MB

    kvprep<<<dim3(64, 16), dim3(256), 0, stream>>>(K, V, kp, vp);
    attn_fwd<<<dim3(16, 32), dim3(512), 0, stream>>>(Q, O, kp, vp);
}

// Round 11
// 162.260 us; speedup vs baseline: 1.2481x; 1.2481x over previous
//
#include <hip/hip_runtime.h>

#define Bn 2
#define Ln 4096
#define Hn 8
#define Dn 64
#define NMEGA 32           // 128-key mega-tiles
#define BH_STRIDE 262144   // halves per bh in kp/vp

typedef float    f32x4  __attribute__((ext_vector_type(4)));
typedef float    f32x16 __attribute__((ext_vector_type(16)));
typedef _Float16 f16x2  __attribute__((ext_vector_type(2)));
typedef _Float16 f16x8  __attribute__((ext_vector_type(8)));
typedef unsigned int u32;
typedef u32 u32x2 __attribute__((ext_vector_type(2)));
typedef u32 u32x4 __attribute__((ext_vector_type(4)));

static __device__ __forceinline__ u32 pkf16(float a, float b){
    auto h = __builtin_amdgcn_cvt_pkrtz(a, b);   // v_cvt_pkrtz_f16_f32
    return __builtin_bit_cast(u32, h);
}

static __device__ __forceinline__ u32x2 swp(u32 a, u32 b){
    auto r = __builtin_amdgcn_permlane32_swap(a, b, false, false);
    return __builtin_bit_cast(u32x2, r);
}

// ---- fused prep, STREAMING REWRITE: no LDS, no barrier, 2048 blocks ----
// Block (t2, bh) handles 32 keys (one g-group of 64-key tile t=t2>>1, g=t2&1).
// Wave w (0..3) emits K unit cc=w and V unit j=w (kh=w>>1, dt=w&1).
// OUTPUT IS BIT-IDENTICAL to the previous kvprep (same RTN casts, same
// layout):
//   kp unit u=g*4+cc, lane l: K[t*64+g*32+(l&31)][cc*16+(l>>5)*8+j]
//   vp unit u=g*4+w,  lane l: V[t*64+g*32+kh*16+(l>>5)*8+j][dt*32+(l&31)]
// K reads: 32 B contiguous per lane. V reads: 8 scalar loads, each
// wave-coalesced (lanes 0-31 = 128 B row segment, lanes 32-63 = next row).
// 8 blocks/CU, ~10 VMEM + 8 cvt + 2 stores per thread -> BW/latency-optimal.
__global__ __launch_bounds__(256)
void kvprep(const float* __restrict__ Kg, const float* __restrict__ Vg,
            _Float16* __restrict__ kp, _Float16* __restrict__ vp){
    const int t2 = blockIdx.x, bh = blockIdx.y, b = bh>>3, h = bh&7;
    const int tid = threadIdx.x;
    const int w = tid >> 6, lane = tid & 63;
    const int l31 = lane & 31, hi = lane >> 5;
    const int t = t2 >> 1, g = t2 & 1;
    _Float16* outbase = (_Float16*)((char*)0) ;  // silence unused-warn pattern
    (void)outbase;

    // ---- K unit cc=w ----
    {
        const float* ks = Kg + (((size_t)b*Ln + t2*32 + l31)*Hn + h)*Dn + w*16 + hi*8;
        float4 a  = *(const float4*)ks;
        float4 c4 = *(const float4*)(ks + 4);
        f16x8 o;
        o[0]=(_Float16)a.x;  o[1]=(_Float16)a.y;  o[2]=(_Float16)a.z;  o[3]=(_Float16)a.w;
        o[4]=(_Float16)c4.x; o[5]=(_Float16)c4.y; o[6]=(_Float16)c4.z; o[7]=(_Float16)c4.w;
        *(f16x8*)(kp + (size_t)bh*BH_STRIDE + (size_t)t*4096
                     + (size_t)(g*4 + w)*512 + (size_t)lane*8) = o;
    }

    // ---- V unit j=w (kh=w>>1, dt=w&1) ----
    {
        const int kh = w >> 1, dt = w & 1;
        const float* vs = Vg + (((size_t)b*Ln + t2*32 + kh*16 + hi*8)*Hn + h)*Dn
                        + dt*32 + l31;
        f16x8 o;
#pragma unroll
        for(int j=0;j<8;++j) o[j] = (_Float16)vs[(size_t)j*Hn*Dn];
        *(f16x8*)(vp + (size_t)bh*BH_STRIDE + (size_t)t*4096
                     + (size_t)(g*4 + w)*512 + (size_t)lane*8) = o;
    }
}

// QK: 4-deep 32x32x16 chain from zero accumulator
static __device__ __forceinline__ f32x16 qk4(const f16x8 (&kf)[4], const f16x8 (&qf)[4]){
    f32x16 s;
#pragma unroll
    for(int r=0;r<16;++r) s[r]=0.f;
    s = __builtin_amdgcn_mfma_f32_32x32x16_f16(kf[0], qf[0], s, 0,0,0);
    s = __builtin_amdgcn_mfma_f32_32x32x16_f16(kf[1], qf[1], s, 0,0,0);
    s = __builtin_amdgcn_mfma_f32_32x32x16_f16(kf[2], qf[2], s, 0,0,0);
    s = __builtin_amdgcn_mfma_f32_32x32x16_f16(kf[3], qf[3], s, 0,0,0);
    return s;
}

// finish: exp2 -> pack (cvt_pkrtz + permlane32_swap) -> consistent-l via fdot2
// -> PV accumulate. Identical op set/order to R5/R8 (bit-identical numerics).
static __device__ __forceinline__ void finish_pv(const f32x16& S, float& lac,
                                                 f32x16& o0, f32x16& o1,
                                                 const f16x8 (&vf)[4]){
    f32x16 p;
#pragma unroll
    for(int r=0;r<16;++r) p[r] = __builtin_amdgcn_exp2f(S[r]);
    u32 A0 = pkf16(p[0],p[1]),   A1 = pkf16(p[2],p[3]);
    u32 B0 = pkf16(p[4],p[5]),   B1 = pkf16(p[6],p[7]);
    u32 C0 = pkf16(p[8],p[9]),   C1 = pkf16(p[10],p[11]);
    u32 D0 = pkf16(p[12],p[13]), D1 = pkf16(p[14],p[15]);
    u32x2 r0 = swp(A0,B0), r1 = swp(A1,B1);
    u32x2 r2 = swp(C0,D0), r3 = swp(C1,D1);
    u32x4 w0 = {r0.x, r1.x, r0.y, r1.y};   // keys [0,16) of this 32-key group
    u32x4 w1 = {r2.x, r3.x, r2.y, r3.y};   // keys [16,32)
    f16x8 pa0 = __builtin_bit_cast(f16x8, w0);
    f16x8 pa1 = __builtin_bit_cast(f16x8, w1);
    const f16x2 ones = {(_Float16)1.0f, (_Float16)1.0f};
#pragma unroll
    for(int j=0;j<4;++j){
        f16x2 c0 = {pa0[2*j], pa0[2*j+1]};
        f16x2 c1 = {pa1[2*j], pa1[2*j+1]};
        lac = __builtin_amdgcn_fdot2(c0, ones, lac, false);
        lac = __builtin_amdgcn_fdot2(c1, ones, lac, false);
    }
    // vf[j], j = kh*2+dt
    o0 = __builtin_amdgcn_mfma_f32_32x32x16_f16(pa0, vf[0], o0, 0,0,0);
    o0 = __builtin_amdgcn_mfma_f32_32x32x16_f16(pa1, vf[2], o0, 0,0,0);
    o1 = __builtin_amdgcn_mfma_f32_32x32x16_f16(pa0, vf[1], o1, 0,0,0);
    o1 = __builtin_amdgcn_mfma_f32_32x32x16_f16(pa1, vf[3], o1, 0,0,0);
}

// load 4 fragment registers (b128 each) from fragment-major global
static __device__ __forceinline__ void ld4(f16x8 (&dst)[4], const char* base, int off){
#pragma unroll
    for(int i=0;i<4;++i) dst[i] = *(const f16x8*)(base + ((off+i)<<10));
}

// ---- main kernel: R8 EXACTLY (best verified: 84.4 us, VGPR 112, no spill) ----
// NO-LDS-staging, free-running waves. kp/vp already in fragment order ->
// direct global loads (L2-resident: XCD bh%8 holds this bh's 2 MB). No
// main-loop barriers. LDS = 35 KB epilogue only. (256,2) -> 128-VGPR cap.
__global__ __launch_bounds__(256,2)
void attn_fwd(const float* __restrict__ Qg, float* __restrict__ Og,
              const _Float16* __restrict__ kp, const _Float16* __restrict__ vp){
    __shared__ __align__(16) float xo[128*68 + 128];   // epilogue combine

    const int tid  = threadIdx.x;
    const int lane = tid & 63, wv = tid >> 6;
    const int qh = wv & 1, kh2 = wv >> 1;
    const int l31 = lane & 31, hi = lane >> 5;
    const int bh = blockIdx.x, b = bh>>3, h = bh&7;
    const int q0 = blockIdx.y*128 + qh*64;

    const float c = 0.125f * 1.4426950408889634f;    // scale * log2(e)

    // Q B-frags: lane holds query=l31, d = cc*16 + hi*8 + j
    f16x8 qf[2][4];
#pragma unroll
    for(int qt=0;qt<2;++qt){
        const float* qrow = Qg + (((size_t)b*Ln + q0 + qt*32 + l31)*Hn + h)*Dn;
#pragma unroll
        for(int cc=0;cc<4;++cc){
            const float* p4 = qrow + cc*16 + hi*8;
            float4 x = *(const float4*)p4;
            float4 y = *(const float4*)(p4+4);
            f16x8 f;
            f[0]=(_Float16)(x.x*c); f[1]=(_Float16)(x.y*c);
            f[2]=(_Float16)(x.z*c); f[3]=(_Float16)(x.w*c);
            f[4]=(_Float16)(y.x*c); f[5]=(_Float16)(y.y*c);
            f[6]=(_Float16)(y.z*c); f[7]=(_Float16)(y.w*c);
            qf[qt][cc]=f;
        }
    }

    f32x16 o[2][2];
    float lac[2] = {0.f, 0.f};
#pragma unroll
    for(int qt=0;qt<2;++qt)
#pragma unroll
        for(int dt=0;dt<2;++dt)
#pragma unroll
            for(int r=0;r<16;++r) o[qt][dt][r]=0.f;

    // per-lane global base of this wave's 64-key half within each mega-tile:
    // mega-tile stride 16 KB; within it: kh2 half (8 KB), unit (1 KB), lane*16.
    const char* kgc = (const char*)(kp + (size_t)bh*BH_STRIDE) + kh2*8192 + lane*16;
    const char* vgc = (const char*)(vp + (size_t)bh*BH_STRIDE) + kh2*8192 + lane*16;

    for(int T=0; T<NMEGA; ++T){
        const char* Kb = kgc + (size_t)T*16384;
        const char* Vb = vgc + (size_t)T*16384;

        f16x8 kf0[4], vf0[4];
        ld4(kf0, Kb, 0); ld4(vf0, Vb, 0);

        f32x16 S0 = qk4(kf0, qf[0]);          // unit (g0,qt0)
        f32x16 S1 = qk4(kf0, qf[1]);          // unit (g0,qt1)

        f16x8 kf1[4], vf1[4];
        ld4(kf1, Kb, 4); ld4(vf1, Vb, 4);

        finish_pv(S0, lac[0], o[0][0], o[0][1], vf0);
        f32x16 S0b = qk4(kf1, qf[0]);         // unit (g1,qt0)
        finish_pv(S1, lac[1], o[1][0], o[1][1], vf0);
        f32x16 S1b = qk4(kf1, qf[1]);         // unit (g1,qt1)
        finish_pv(S0b, lac[0], o[0][0], o[0][1], vf1);
        finish_pv(S1b, lac[1], o[1][0], o[1][1], vf1);
    }

    // ---- reduce l within wave: lanes l and l+32 cover complementary key slots ----
    float lred[2];
#pragma unroll
    for(int qt=0;qt<2;++qt)
        lred[qt] = lac[qt] + __shfl_xor(lac[qt], 32, 64);

    // ---- epilogue: combine kh2 halves through LDS ----
    float* xl = xo + 128*68;
    if(kh2){
#pragma unroll
        for(int qt=0;qt<2;++qt){
#pragma unroll
            for(int dt=0;dt<2;++dt)
#pragma unroll
                for(int r=0;r<16;++r){
                    int qr = (r&3) + 8*(r>>2) + 4*hi;
                    xo[(qh*64 + qt*32 + qr)*68 + dt*32 + l31] = o[qt][dt][r];
                }
            if(hi==0) xl[qh*64 + qt*32 + l31] = lred[qt];
        }
    }
    __syncthreads();
    if(!kh2){
#pragma unroll
        for(int qt=0;qt<2;++qt){
            float inv = 1.0f/(lred[qt] + xl[qh*64 + qt*32 + l31]);
            float* ob = Og + (((size_t)b*Ln + q0 + qt*32)*Hn + h)*Dn;
#pragma unroll
            for(int r=0;r<16;++r){
                int qr = (r&3) + 8*(r>>2) + 4*hi;
                float invr = __shfl(inv, qr, 64);   // lane qr holds query qr's inv
#pragma unroll
                for(int dt=0;dt<2;++dt){
                    float val = o[qt][dt][r] + xo[(qh*64 + qt*32 + qr)*68 + dt*32 + l31];
                    ob[(size_t)qr*Hn*Dn + dt*32 + l31] = val*invr;
                }
            }
        }
    }
}

extern "C" void kernel_launch(void* const* d_in, const int* in_sizes, int n_in,
                              void* d_out, int out_size, void* d_ws, size_t ws_size,
                              hipStream_t stream) {
    const float* Q = (const float*)d_in[0];
    const float* K = (const float*)d_in[1];
    const float* V = (const float*)d_in[2];
    float* O = (float*)d_out;

    _Float16* kp = (_Float16*)d_ws;                        // 8 MB
    _Float16* vp = (_Float16*)((char*)d_ws + (8u<<20));    // 8 MB

    kvprep<<<dim3(128, 16), dim3(256), 0, stream>>>(K, V, kp, vp);
    attn_fwd<<<dim3(16, 32), dim3(256), 0, stream>>>(Q, O, kp, vp);
}